// Round 1
// baseline (454.763 us; speedup 1.0000x reference)
//
#include <hip/hip_runtime.h>

// Problem constants
#define BATCH 64
#define CIN   128
#define HIN   56
#define WIN   56
#define COUT  256
#define KSZ   3
#define OHP   54
#define OWP   54
#define NSPAT (OHP * OWP)            // 2916 flat spatial outputs per batch
#define NFLAT (BATCH * NSPAT)        // 186624 = 729 * 256 exactly
#define KDIM  (CIN * KSZ * KSZ)      // 1152 = 18 * 64
#define NBLK  (NFLAT / 256)          // 729 conv blocks (256x256 tiles)
#define NCAST (BATCH * HIN)          // 3584 cast blocks
#define NQNT  ((COUT * KDIM) / 256)  // 1152 quant blocks

typedef short bf16x8 __attribute__((ext_vector_type(8)));
typedef float f32x4  __attribute__((ext_vector_type(4)));

static __device__ __forceinline__ unsigned short f2bf(float f) {
    unsigned v = __float_as_uint(f);
    v += 0x7FFFu + ((v >> 16) & 1u);
    return (unsigned short)(v >> 16);
}

static __device__ __forceinline__ void gl_lds16(const void* g, void* l) {
    __builtin_amdgcn_global_load_lds(
        (const __attribute__((address_space(1))) void*)g,
        (__attribute__((address_space(3))) void*)l, 16, 0, 0);
}

// Raw barriers / counted waits: __syncthreads() would emit vmcnt(0) and kill the pipeline.
#define BAR()   asm volatile("s_barrier" ::: "memory")
#define LGKM0() asm volatile("s_waitcnt lgkmcnt(0)" ::: "memory")
#define VMC2()  asm volatile("s_waitcnt vmcnt(2)" ::: "memory")
#define VMC0()  asm volatile("s_waitcnt vmcnt(0)" ::: "memory")
#define SB0()   __builtin_amdgcn_sched_barrier(0)

// ---------------- kernel 1: per-block max |w| ----------------
__global__ __launch_bounds__(256) void maxabs_kernel(const float* __restrict__ w,
                                                     float* __restrict__ blockmax, int n) {
    float m = 0.f;
    for (int i = blockIdx.x * 256 + threadIdx.x; i < n; i += gridDim.x * 256)
        m = fmaxf(m, fabsf(w[i]));
    for (int off = 32; off > 0; off >>= 1)
        m = fmaxf(m, __shfl_down(m, off));
    __shared__ float red[4];
    if ((threadIdx.x & 63) == 0) red[threadIdx.x >> 6] = m;
    __syncthreads();
    if (threadIdx.x == 0)
        blockmax[blockIdx.x] = fmaxf(fmaxf(red[0], red[1]), fmaxf(red[2], red[3]));
}

// ---------------- kernel 2: fused cast (NCHW->bf16 NHWC) + quantize/repack ----------------
// blocks [0, NCAST): cast; blocks [NCAST, NCAST+NQNT): quant. Both depend only on maxabs/x/w.
__global__ __launch_bounds__(256) void prep_kernel(const float* __restrict__ x,
                                                   const float* __restrict__ w,
                                                   const float* __restrict__ wp,
                                                   const float* __restrict__ wn,
                                                   const float* __restrict__ blockmax,
                                                   unsigned short* __restrict__ qw,
                                                   unsigned* __restrict__ xt_u32) {
    int bid = blockIdx.x;
    if (bid < NCAST) {
        int b = bid / HIN;
        int h = bid - b * HIN;
        __shared__ float xs[CIN][57];
#pragma unroll
        for (int it = 0; it < 7; ++it) {
            int id = it * 256 + threadIdx.x;       // 1792 float4 chunks: 128 ci x 14
            int ci = id / 14;
            int wq = (id - ci * 14) * 4;
            float4 v = *(const float4*)(x + (((size_t)(b * CIN + ci)) * HIN + h) * WIN + wq);
            xs[ci][wq + 0] = v.x; xs[ci][wq + 1] = v.y;
            xs[ci][wq + 2] = v.z; xs[ci][wq + 3] = v.w;
        }
        __syncthreads();
#pragma unroll
        for (int it = 0; it < 7; ++it) {
            int id = it * 256 + threadIdx.x;       // 56 w x 32 chunks of 4 ci
            int w_ = id >> 5;
            int cq = (id & 31) * 4;
            unsigned u0 = (unsigned)f2bf(xs[cq + 0][w_]) | ((unsigned)f2bf(xs[cq + 1][w_]) << 16);
            unsigned u1 = (unsigned)f2bf(xs[cq + 2][w_]) | ((unsigned)f2bf(xs[cq + 3][w_]) << 16);
            uint2 val; val.x = u0; val.y = u1;
            *(uint2*)&xt_u32[((size_t)(b * HIN + h) * WIN + w_) * 64 + (id & 31) * 2] = val;
        }
    } else {
        __shared__ float red[4];
        float m = blockmax[threadIdx.x];          // 256 partial maxima
        for (int off = 32; off > 0; off >>= 1)
            m = fmaxf(m, __shfl_down(m, off));
        if ((threadIdx.x & 63) == 0) red[threadIdx.x >> 6] = m;
        __syncthreads();
        float t = 0.05f * fmaxf(fmaxf(red[0], red[1]), fmaxf(red[2], red[3]));

        int idx = (bid - NCAST) * 256 + threadIdx.x;
        float p = fabsf(wp[0]), nn = fabsf(wn[0]);
        float v = w[idx];
        float qv = (v > t) ? p : ((v < -t) ? -nn : 0.0f);
        int co  = idx / KDIM;
        int rem = idx - co * KDIM;
        int ci  = rem / 9;
        int kk  = rem - ci * 9;            // kh*3+kw
        // qw layout: [co][kk*128 + ci] bf16  (k contiguous per co row)
        qw[co * KDIM + kk * CIN + ci] = f2bf(qv);
    }
}

// ---------------- kernel 3: implicit-GEMM MFMA conv, 256x256 tile, 4-phase counted-vmcnt ----
// BM=256 (all co), BN=256 (flat n over all batches: 729*256 = 186624 exact), BK=64, 18 K-tiles.
// 512 threads = 8 waves (2M x 4N); per-wave output 128co x 64n = acc[8][4] f32x4.
// LDS: 2 slots x (A 32KB + B 32KB) = 128 KiB. Staging: 8 gl_lds16 calls/tile
// (A calls c=0..3 cover rows 64c..64c+63; B likewise), XOR-8 pre-swizzled source.
//
// Pipeline ledger (per wave, verified by induction; vmcnt retires OLDEST first):
//   stage order for tile T+1 (issued during tile T): [B0,B1 @p0 | B2,B3 @p1 | A0,A2 @p2 | A1,A3 @p3]
//   p0 needs (tile T): all B + A0,A2  -> confirmed by p3's VMC2 of tile T-1
//   p1 needs (tile T): A1,A3          -> confirmed by p0's VMC2
//   prologue: issue tile0's 8 calls in same order, VMC2 (A1,A3 left in flight), BAR.
//   steady state: outstanding never exceeds 8, never drains below 2 except last tile.
__global__ __launch_bounds__(512, 2) void conv_mfma_kernel(const unsigned short* __restrict__ xt,
                                                           const unsigned short* __restrict__ qw,
                                                           const float* __restrict__ bias,
                                                           float* __restrict__ out) {
    // bijective XCD swizzle (729 = 8*91 + 1): consecutive wgid on one XCD -> L2 locality for xt
    unsigned orig = blockIdx.x;
    unsigned xcd = orig & 7u, loc = orig >> 3;
    const unsigned q91 = NBLK / 8u, r1 = NBLK % 8u;  // 91, 1
    unsigned wgid = (xcd < r1 ? xcd * (q91 + 1) : r1 * (q91 + 1) + (xcd - r1) * q91) + loc;
    unsigned n0 = wgid * 256u;

    __shared__ __align__(16) unsigned short sm[2][32768];  // [slot][A: 0..16384 | B: 16384..32768] shorts

    const int tid   = threadIdx.x;
    const int wave  = tid >> 6, lane = tid & 63;
    const int wrow  = wave >> 2;          // 0..1  (M half: co rows wrow*128..)
    const int wcol  = wave & 3;           // 0..3  (N quarter: n cols wcol*64..)
    const int quad  = lane >> 4, r16 = lane & 15;
    const int row_s = tid >> 3;                       // staging row within a 64-row call
    const int lc    = (tid & 7) ^ (row_s & 7);        // XOR-8: logical chunk fetched (same for all calls)

    // A source base (shorts): qw[row][k]; call c adds c*64 rows, tile kt adds kt*64 k
    const unsigned short* Ag = qw + (size_t)row_s * KDIM + lc * 8;
    // B row pointers per call (flat n -> (b, oh, ow); all rows valid, no clamping needed)
    const unsigned short* Bg[4];
#pragma unroll
    for (int c = 0; c < 4; ++c) {
        unsigned n = n0 + c * 64 + row_s;
        unsigned b = n / NSPAT, rem = n - b * NSPAT;
        unsigned oh = rem / OWP, ow = rem - oh * OWP;
        Bg[c] = xt + ((size_t)((b * HIN + oh) * WIN + ow)) * CIN + lc * 8;
    }

    auto stA = [&](int slot, int c, int kt) {
        gl_lds16(Ag + (size_t)c * (64 * KDIM) + kt * 64,
                 (char*)sm + slot * 65536 + c * 8192 + wave * 1024);
    };
    auto stB = [&](int slot, int c, int boff) {
        gl_lds16(Bg[c] + boff,
                 (char*)sm + slot * 65536 + 32768 + c * 8192 + wave * 1024);
    };

    f32x4 acc[8][4] = {};

    const int pc0 = (quad ^ (r16 & 7)) * 8;        // phys chunk (shorts), k-half s=0
    const int pc1 = ((4 + quad) ^ (r16 & 7)) * 8;  // k-half s=1
    const int ar  = wrow * 128 + r16;              // A base row for this lane
    const int br  = wcol * 64  + r16;              // B base row for this lane

#define MROW(I, AF) \
    acc[I][0] = __builtin_amdgcn_mfma_f32_16x16x32_bf16(AF, bfr0, acc[I][0], 0, 0, 0); \
    acc[I][1] = __builtin_amdgcn_mfma_f32_16x16x32_bf16(AF, bfr1, acc[I][1], 0, 0, 0); \
    acc[I][2] = __builtin_amdgcn_mfma_f32_16x16x32_bf16(AF, bfr2, acc[I][2], 0, 0, 0); \
    acc[I][3] = __builtin_amdgcn_mfma_f32_16x16x32_bf16(AF, bfr3, acc[I][3], 0, 0, 0);

    // ---- prologue: stage tile 0, order B0,B1,B2,B3,A0,A2,A1,A3; confirm first 6 ----
    {
        stB(0, 0, 0); stB(0, 1, 0); stB(0, 2, 0); stB(0, 3, 0);
        stA(0, 0, 0); stA(0, 2, 0); stA(0, 1, 0); stA(0, 3, 0);
        VMC2(); BAR();
    }

#pragma unroll
    for (int t = 0; t < 18; ++t) {
        const int cur = t & 1, nxt = cur ^ 1;
        const int t1  = t + 1;
        const int sl1 = t1 >> 1;
        const int kh1 = sl1 / 3, kw1 = sl1 - 3 * (sl1 / 3);
        const int boff1 = (kh1 * WIN + kw1) * CIN + (t1 & 1) * 64;   // shorts (dead at t=17)
        const unsigned short* Ac = &sm[cur][0];
        const unsigned short* Bc = &sm[cur][16384];

        bf16x8 af0, af1, af2, af3, bfr0, bfr1, bfr2, bfr3;

        // ---- phase 0: k-half 0, acc rows 0..3 (+ B frags) ----
        af0  = *(const bf16x8*)&Ac[(ar +  0) * 64 + pc0];
        af1  = *(const bf16x8*)&Ac[(ar + 16) * 64 + pc0];
        af2  = *(const bf16x8*)&Ac[(ar + 32) * 64 + pc0];
        af3  = *(const bf16x8*)&Ac[(ar + 48) * 64 + pc0];
        bfr0 = *(const bf16x8*)&Bc[(br +  0) * 64 + pc0];
        bfr1 = *(const bf16x8*)&Bc[(br + 16) * 64 + pc0];
        bfr2 = *(const bf16x8*)&Bc[(br + 32) * 64 + pc0];
        bfr3 = *(const bf16x8*)&Bc[(br + 48) * 64 + pc0];
        if (t < 17) { stB(nxt, 0, boff1); stB(nxt, 1, boff1); }
        BAR(); LGKM0(); SB0();
        __builtin_amdgcn_s_setprio(1);
        MROW(0, af0) MROW(1, af1) MROW(2, af2) MROW(3, af3)
        __builtin_amdgcn_s_setprio(0); SB0();
        if (t < 17) { VMC2(); } else { VMC0(); }   // confirm this tile's A1,A3
        BAR();

        // ---- phase 1: k-half 0, acc rows 4..7 ----
        af0 = *(const bf16x8*)&Ac[(ar +  64) * 64 + pc0];
        af1 = *(const bf16x8*)&Ac[(ar +  80) * 64 + pc0];
        af2 = *(const bf16x8*)&Ac[(ar +  96) * 64 + pc0];
        af3 = *(const bf16x8*)&Ac[(ar + 112) * 64 + pc0];
        if (t < 17) { stB(nxt, 2, boff1); stB(nxt, 3, boff1); }
        BAR(); LGKM0(); SB0();
        __builtin_amdgcn_s_setprio(1);
        MROW(4, af0) MROW(5, af1) MROW(6, af2) MROW(7, af3)
        __builtin_amdgcn_s_setprio(0); SB0();
        BAR();

        // ---- phase 2: k-half 1, acc rows 0..3 (+ B frags at pc1) ----
        af0  = *(const bf16x8*)&Ac[(ar +  0) * 64 + pc1];
        af1  = *(const bf16x8*)&Ac[(ar + 16) * 64 + pc1];
        af2  = *(const bf16x8*)&Ac[(ar + 32) * 64 + pc1];
        af3  = *(const bf16x8*)&Ac[(ar + 48) * 64 + pc1];
        bfr0 = *(const bf16x8*)&Bc[(br +  0) * 64 + pc1];
        bfr1 = *(const bf16x8*)&Bc[(br + 16) * 64 + pc1];
        bfr2 = *(const bf16x8*)&Bc[(br + 32) * 64 + pc1];
        bfr3 = *(const bf16x8*)&Bc[(br + 48) * 64 + pc1];
        if (t < 17) { stA(nxt, 0, t1); stA(nxt, 2, t1); }
        BAR(); LGKM0(); SB0();
        __builtin_amdgcn_s_setprio(1);
        MROW(0, af0) MROW(1, af1) MROW(2, af2) MROW(3, af3)
        __builtin_amdgcn_s_setprio(0); SB0();
        BAR();

        // ---- phase 3: k-half 1, acc rows 4..7 ----
        af0 = *(const bf16x8*)&Ac[(ar +  64) * 64 + pc1];
        af1 = *(const bf16x8*)&Ac[(ar +  80) * 64 + pc1];
        af2 = *(const bf16x8*)&Ac[(ar +  96) * 64 + pc1];
        af3 = *(const bf16x8*)&Ac[(ar + 112) * 64 + pc1];
        if (t < 17) { stA(nxt, 1, t1); stA(nxt, 3, t1); }
        BAR(); LGKM0(); SB0();
        __builtin_amdgcn_s_setprio(1);
        MROW(4, af0) MROW(5, af1) MROW(6, af2) MROW(7, af3)
        __builtin_amdgcn_s_setprio(0); SB0();
        if (t < 17) { VMC2(); }                     // confirm next tile's B0-3,A0,A2
        BAR();
    }
#undef MROW

    // ---- epilogue: D row m = quad*4 + r (co side), col n = r16 (layout verified) ----
#pragma unroll
    for (int j = 0; j < 4; ++j) {
        unsigned n = n0 + wcol * 64 + j * 16 + r16;
        unsigned b = n / NSPAT, rem = n - b * NSPAT;
        size_t ob = (size_t)b * COUT * NSPAT + rem;
#pragma unroll
        for (int i = 0; i < 8; ++i) {
            int co = wrow * 128 + i * 16 + quad * 4;
            float4 bv = *(const float4*)(bias + co);
            size_t o = ob + (size_t)co * NSPAT;
            out[o]             = acc[i][j][0] + bv.x;
            out[o + NSPAT]     = acc[i][j][1] + bv.y;
            out[o + 2 * NSPAT] = acc[i][j][2] + bv.z;
            out[o + 3 * NSPAT] = acc[i][j][3] + bv.w;
        }
    }
}

extern "C" void kernel_launch(void* const* d_in, const int* in_sizes, int n_in,
                              void* d_out, int out_size, void* d_ws, size_t ws_size,
                              hipStream_t stream) {
    const float* x      = (const float*)d_in[0];
    const float* weight = (const float*)d_in[1];
    const float* bias   = (const float*)d_in[2];
    const float* wp     = (const float*)d_in[3];
    const float* wn     = (const float*)d_in[4];
    float* out          = (float*)d_out;

    // ws layout: [0,1024) blockmax fp32[256] | [1024,..) qw bf16 [256][1152]
    //            [590848,..) x_t bf16 [64][56][56][128]
    float*          bmax = (float*)d_ws;
    unsigned short* qw   = (unsigned short*)((char*)d_ws + 1024);
    unsigned short* xt   = (unsigned short*)((char*)d_ws + 590848);

    maxabs_kernel<<<256, 256, 0, stream>>>(weight, bmax, COUT * KDIM);
    prep_kernel<<<NCAST + NQNT, 256, 0, stream>>>(x, weight, wp, wn, bmax, qw, (unsigned*)xt);
    conv_mfma_kernel<<<NBLK, 512, 0, stream>>>(xt, qw, bias, out);
}

// Round 2
// 448.251 us; speedup vs baseline: 1.0145x; 1.0145x over previous
//
#include <hip/hip_runtime.h>

// Problem constants
#define BATCH 64
#define CIN   128
#define HIN   56
#define WIN   56
#define COUT  256
#define KSZ   3
#define OHP   54
#define OWP   54
#define NSPAT (OHP * OWP)            // 2916 flat spatial outputs per batch
#define NFLAT (BATCH * NSPAT)        // 186624 = 729 * 256 exactly
#define KDIM  (CIN * KSZ * KSZ)      // 1152 = 18 * 64
#define NBLK  (NFLAT / 256)          // 729 conv blocks (256x256 tiles)

typedef short bf16x8 __attribute__((ext_vector_type(8)));
typedef float f32x4  __attribute__((ext_vector_type(4)));

static __device__ __forceinline__ unsigned short f2bf(float f) {
    unsigned v = __float_as_uint(f);
    v += 0x7FFFu + ((v >> 16) & 1u);
    return (unsigned short)(v >> 16);
}

static __device__ __forceinline__ void gl_lds16(const void* g, void* l) {
    __builtin_amdgcn_global_load_lds(
        (const __attribute__((address_space(1))) void*)g,
        (__attribute__((address_space(3))) void*)l, 16, 0, 0);
}

// Raw barrier + counted vmcnt: __syncthreads() would emit vmcnt(0) and drain the pipeline.
#define BAR()   asm volatile("s_barrier" ::: "memory")
#define VMC2()  asm volatile("s_waitcnt vmcnt(2)" ::: "memory")
#define VMC0()  asm volatile("s_waitcnt vmcnt(0)" ::: "memory")

// ---------------- kernel 1: per-block max |w| (no atomics, no init needed) ----------------
__global__ __launch_bounds__(256) void maxabs_kernel(const float* __restrict__ w,
                                                     float* __restrict__ blockmax, int n) {
    float m = 0.f;
    for (int i = blockIdx.x * 256 + threadIdx.x; i < n; i += gridDim.x * 256)
        m = fmaxf(m, fabsf(w[i]));
    for (int off = 32; off > 0; off >>= 1)
        m = fmaxf(m, __shfl_down(m, off));
    __shared__ float red[4];
    if ((threadIdx.x & 63) == 0) red[threadIdx.x >> 6] = m;
    __syncthreads();
    if (threadIdx.x == 0)
        blockmax[blockIdx.x] = fmaxf(fmaxf(red[0], red[1]), fmaxf(red[2], red[3]));
}

// ---------------- kernel 2: finish max-reduce + ternary quantize + repack ----------------
// qw layout: [co][(kh*3+kw)*128 + ci] bf16
__global__ __launch_bounds__(256) void quant_kernel(const float* __restrict__ w,
                                                    const float* __restrict__ wp,
                                                    const float* __restrict__ wn,
                                                    const float* __restrict__ blockmax,
                                                    unsigned short* __restrict__ qw) {
    __shared__ float red[4];
    float m = blockmax[threadIdx.x];          // 256 partial maxima
    for (int off = 32; off > 0; off >>= 1)
        m = fmaxf(m, __shfl_down(m, off));
    if ((threadIdx.x & 63) == 0) red[threadIdx.x >> 6] = m;
    __syncthreads();
    float t = 0.05f * fmaxf(fmaxf(red[0], red[1]), fmaxf(red[2], red[3]));

    int idx = blockIdx.x * 256 + threadIdx.x;   // grid covers exactly 294912
    float p = fabsf(wp[0]), nn = fabsf(wn[0]);
    float v = w[idx];
    float q = (v > t) ? p : ((v < -t) ? -nn : 0.0f);
    int co  = idx / KDIM;
    int rem = idx - co * KDIM;
    int ci  = rem / 9;
    int kk  = rem - ci * 9;            // kh*3+kw
    qw[co * KDIM + kk * CIN + ci] = f2bf(q);
}

// ---------------- kernel 3: x fp32 NCHW -> bf16 NHWC (x_t[b][h][w][ci]) ----------------
__global__ __launch_bounds__(256) void cast_nhwc_kernel(const float* __restrict__ x,
                                                        unsigned* __restrict__ xt_u32) {
    int b = blockIdx.x / HIN;
    int h = blockIdx.x - b * HIN;
    __shared__ float xs[CIN][57];
#pragma unroll
    for (int it = 0; it < 7; ++it) {
        int id = it * 256 + threadIdx.x;       // 1792 float4 chunks: 128 ci x 14
        int ci = id / 14;
        int wq = (id - ci * 14) * 4;
        float4 v = *(const float4*)(x + (((size_t)(b * CIN + ci)) * HIN + h) * WIN + wq);
        xs[ci][wq + 0] = v.x; xs[ci][wq + 1] = v.y;
        xs[ci][wq + 2] = v.z; xs[ci][wq + 3] = v.w;
    }
    __syncthreads();
#pragma unroll
    for (int it = 0; it < 7; ++it) {
        int id = it * 256 + threadIdx.x;       // 56 w x 32 chunks of 4 ci
        int w_ = id >> 5;
        int cq = (id & 31) * 4;
        unsigned u0 = (unsigned)f2bf(xs[cq + 0][w_]) | ((unsigned)f2bf(xs[cq + 1][w_]) << 16);
        unsigned u1 = (unsigned)f2bf(xs[cq + 2][w_]) | ((unsigned)f2bf(xs[cq + 3][w_]) << 16);
        uint2 val; val.x = u0; val.y = u1;
        *(uint2*)&xt_u32[((size_t)(b * HIN + h) * WIN + w_) * 64 + (id & 31) * 2] = val;
    }
}

// ---------------- kernel 4: implicit-GEMM MFMA conv, 256x256 tile ----------------
// BM=256 (all co), BN=256 (flat n: 729*256 = 186624 exact), BK=64, 18 K-tiles.
// 512 threads = 8 waves (2M x 4N); per-wave output 128co x 64n = acc[8][4] f32x4.
// LDS: 2 slots x (A 32KB + B 32KB) = 128 KiB -> 1 block/CU, 2 waves/SIMD.
//
// Sync structure: TWO barriers per K-tile (same cadence as the proven round-0 kernel)
// with COUNTED vmcnt instead of drain-0. Per-wave ledger (vmcnt retires oldest first;
// stage order per tile: B0,B1 | B2,B3 | A0,A2 | A1,A3):
//   invariant entering tile t: outstanding = [A1,A3] (this tile's late A loads)
//   Q0:  +B0',B1' -> 4;  VMC2 retires A1,A3 (needed by Q1's reads)   -> mid BAR
//   Q1:  +B2',B3' -> 4
//   Q2:  +A0',A2' -> 6
//   Q3:  +A1',A3' -> 8;  VMC2 retires B0'..B3',A0',A2' (needed by next
//        tile's Q0 reads), leaves [A1',A3']                          -> tile-end BAR
// All other hazards (k-half / group transitions within confirmed data) need no sync;
// compiler inserts fine-grained lgkmcnt for ds_read->MFMA (documented near-optimal).
__global__ __launch_bounds__(512, 2) void conv_mfma_kernel(const unsigned short* __restrict__ xt,
                                                           const unsigned short* __restrict__ qw,
                                                           const float* __restrict__ bias,
                                                           float* __restrict__ out) {
    // bijective XCD swizzle (729 = 8*91 + 1): consecutive wgid on one XCD -> L2 locality
    unsigned orig = blockIdx.x;
    unsigned xcd = orig & 7u, loc = orig >> 3;
    const unsigned q91 = NBLK / 8u, r1 = NBLK % 8u;  // 91, 1
    unsigned wgid = (xcd < r1 ? xcd * (q91 + 1) : r1 * (q91 + 1) + (xcd - r1) * q91) + loc;
    unsigned n0 = wgid * 256u;

    __shared__ __align__(16) unsigned short sm[2][32768];  // [slot][A: 0..16384 | B: 16384..32768]

    const int tid   = threadIdx.x;
    const int wave  = tid >> 6, lane = tid & 63;
    const int wrow  = wave >> 2;          // 0..1  (co half)
    const int wcol  = wave & 3;           // 0..3  (n quarter)
    const int quad  = lane >> 4, r16 = lane & 15;
    const int row_s = tid >> 3;                       // staging row within a 64-row call
    const int lc    = (tid & 7) ^ (row_s & 7);        // XOR-8 pre-swizzled source chunk

    const unsigned short* Ag = qw + (size_t)row_s * KDIM + lc * 8;
    const unsigned short* Bg[4];
#pragma unroll
    for (int c = 0; c < 4; ++c) {
        unsigned n = n0 + c * 64 + row_s;
        unsigned b = n / NSPAT, rem = n - b * NSPAT;
        unsigned oh = rem / OWP, ow = rem - oh * OWP;
        Bg[c] = xt + ((size_t)((b * HIN + oh) * WIN + ow)) * CIN + lc * 8;
    }

    auto stA = [&](int slot, int c, int kt) {
        gl_lds16(Ag + (size_t)c * (64 * KDIM) + kt * 64,
                 (char*)sm + slot * 65536 + c * 8192 + wave * 1024);
    };
    auto stB = [&](int slot, int c, int boff) {
        gl_lds16(Bg[c] + boff,
                 (char*)sm + slot * 65536 + 32768 + c * 8192 + wave * 1024);
    };

    f32x4 acc[8][4] = {};

    const int pc0 = (quad ^ (r16 & 7)) * 8;        // phys chunk (shorts), k-half 0
    const int pc1 = ((4 + quad) ^ (r16 & 7)) * 8;  // k-half 1
    const int ar  = wrow * 128 + r16;              // A base row for this lane
    const int br  = wcol * 64  + r16;              // B base row for this lane

#define MROW(I, AF) \
    acc[I][0] = __builtin_amdgcn_mfma_f32_16x16x32_bf16(AF, bfr0, acc[I][0], 0, 0, 0); \
    acc[I][1] = __builtin_amdgcn_mfma_f32_16x16x32_bf16(AF, bfr1, acc[I][1], 0, 0, 0); \
    acc[I][2] = __builtin_amdgcn_mfma_f32_16x16x32_bf16(AF, bfr2, acc[I][2], 0, 0, 0); \
    acc[I][3] = __builtin_amdgcn_mfma_f32_16x16x32_bf16(AF, bfr3, acc[I][3], 0, 0, 0);

    // ---- prologue: stage tile 0 in ledger order, confirm first 6, leave A1,A3 in flight ----
    {
        stB(0, 0, 0); stB(0, 1, 0); stB(0, 2, 0); stB(0, 3, 0);
        stA(0, 0, 0); stA(0, 2, 0); stA(0, 1, 0); stA(0, 3, 0);
        VMC2(); BAR();
    }

#pragma unroll
    for (int t = 0; t < 18; ++t) {
        const int cur = t & 1, nxt = cur ^ 1;
        const int t1  = t + 1;
        const int sl1 = t1 >> 1;
        const int kh1 = sl1 / 3, kw1 = sl1 - 3 * kh1;
        const int boff1 = (kh1 * WIN + kw1) * CIN + (t1 & 1) * 64;   // shorts (dead at t=17)
        const unsigned short* Ac = &sm[cur][0];
        const unsigned short* Bc = &sm[cur][16384];

        bf16x8 af0, af1, af2, af3, bfr0, bfr1, bfr2, bfr3;

        // ---- Q0: k-half 0, acc rows 0..3 ----
        if (t < 17) { stB(nxt, 0, boff1); stB(nxt, 1, boff1); }
        af0  = *(const bf16x8*)&Ac[(ar +  0) * 64 + pc0];
        af1  = *(const bf16x8*)&Ac[(ar + 16) * 64 + pc0];
        af2  = *(const bf16x8*)&Ac[(ar + 32) * 64 + pc0];
        af3  = *(const bf16x8*)&Ac[(ar + 48) * 64 + pc0];
        bfr0 = *(const bf16x8*)&Bc[(br +  0) * 64 + pc0];
        bfr1 = *(const bf16x8*)&Bc[(br + 16) * 64 + pc0];
        bfr2 = *(const bf16x8*)&Bc[(br + 32) * 64 + pc0];
        bfr3 = *(const bf16x8*)&Bc[(br + 48) * 64 + pc0];
        __builtin_amdgcn_s_setprio(1);
        MROW(0, af0) MROW(1, af1) MROW(2, af2) MROW(3, af3)
        __builtin_amdgcn_s_setprio(0);
        if (t < 17) { VMC2(); } else { VMC0(); }   // confirm this tile's A1,A3
        BAR();                                     // mid-tile: group-1 A regions now safe

        // ---- Q1: k-half 0, acc rows 4..7 ----
        if (t < 17) { stB(nxt, 2, boff1); stB(nxt, 3, boff1); }
        af0 = *(const bf16x8*)&Ac[(ar +  64) * 64 + pc0];
        af1 = *(const bf16x8*)&Ac[(ar +  80) * 64 + pc0];
        af2 = *(const bf16x8*)&Ac[(ar +  96) * 64 + pc0];
        af3 = *(const bf16x8*)&Ac[(ar + 112) * 64 + pc0];
        __builtin_amdgcn_s_setprio(1);
        MROW(4, af0) MROW(5, af1) MROW(6, af2) MROW(7, af3)
        __builtin_amdgcn_s_setprio(0);

        // ---- Q2: k-half 1, acc rows 0..3 ----
        if (t < 17) { stA(nxt, 0, t1); stA(nxt, 2, t1); }
        af0  = *(const bf16x8*)&Ac[(ar +  0) * 64 + pc1];
        af1  = *(const bf16x8*)&Ac[(ar + 16) * 64 + pc1];
        af2  = *(const bf16x8*)&Ac[(ar + 32) * 64 + pc1];
        af3  = *(const bf16x8*)&Ac[(ar + 48) * 64 + pc1];
        bfr0 = *(const bf16x8*)&Bc[(br +  0) * 64 + pc1];
        bfr1 = *(const bf16x8*)&Bc[(br + 16) * 64 + pc1];
        bfr2 = *(const bf16x8*)&Bc[(br + 32) * 64 + pc1];
        bfr3 = *(const bf16x8*)&Bc[(br + 48) * 64 + pc1];
        __builtin_amdgcn_s_setprio(1);
        MROW(0, af0) MROW(1, af1) MROW(2, af2) MROW(3, af3)
        __builtin_amdgcn_s_setprio(0);

        // ---- Q3: k-half 1, acc rows 4..7 ----
        if (t < 17) { stA(nxt, 1, t1); stA(nxt, 3, t1); }
        af0 = *(const bf16x8*)&Ac[(ar +  64) * 64 + pc1];
        af1 = *(const bf16x8*)&Ac[(ar +  80) * 64 + pc1];
        af2 = *(const bf16x8*)&Ac[(ar +  96) * 64 + pc1];
        af3 = *(const bf16x8*)&Ac[(ar + 112) * 64 + pc1];
        __builtin_amdgcn_s_setprio(1);
        MROW(4, af0) MROW(5, af1) MROW(6, af2) MROW(7, af3)
        __builtin_amdgcn_s_setprio(0);
        if (t < 17) {
            VMC2();   // confirm next tile's B0-3,A0,A2; leave A1',A3' in flight
            BAR();    // tile-end
        }
    }
#undef MROW

    // ---- epilogue: D row m = quad*4 + r (co side), col n = r16 (layout verified) ----
#pragma unroll
    for (int j = 0; j < 4; ++j) {
        unsigned n = n0 + wcol * 64 + j * 16 + r16;
        unsigned b = n / NSPAT, rem = n - b * NSPAT;
        size_t ob = (size_t)b * COUT * NSPAT + rem;
#pragma unroll
        for (int i = 0; i < 8; ++i) {
            int co = wrow * 128 + i * 16 + quad * 4;
            float4 bv = *(const float4*)(bias + co);
            size_t o = ob + (size_t)co * NSPAT;
            out[o]             = acc[i][j][0] + bv.x;
            out[o + NSPAT]     = acc[i][j][1] + bv.y;
            out[o + 2 * NSPAT] = acc[i][j][2] + bv.z;
            out[o + 3 * NSPAT] = acc[i][j][3] + bv.w;
        }
    }
}

extern "C" void kernel_launch(void* const* d_in, const int* in_sizes, int n_in,
                              void* d_out, int out_size, void* d_ws, size_t ws_size,
                              hipStream_t stream) {
    const float* x      = (const float*)d_in[0];
    const float* weight = (const float*)d_in[1];
    const float* bias   = (const float*)d_in[2];
    const float* wp     = (const float*)d_in[3];
    const float* wn     = (const float*)d_in[4];
    float* out          = (float*)d_out;

    // ws layout: [0,1024) blockmax fp32[256] | [1024,..) qw bf16 [256][1152]
    //            [590848,..) x_t bf16 [64][56][56][128]
    float*          bmax = (float*)d_ws;
    unsigned short* qw   = (unsigned short*)((char*)d_ws + 1024);
    unsigned short* xt   = (unsigned short*)((char*)d_ws + 590848);

    maxabs_kernel<<<256, 256, 0, stream>>>(weight, bmax, COUT * KDIM);
    quant_kernel<<<(COUT * KDIM) / 256, 256, 0, stream>>>(weight, wp, wn, bmax, qw);
    cast_nhwc_kernel<<<BATCH * HIN, 256, 0, stream>>>(x, (unsigned*)xt);
    conv_mfma_kernel<<<NBLK, 512, 0, stream>>>(xt, qw, bias, out);
}

// Round 3
// 384.119 us; speedup vs baseline: 1.1839x; 1.1670x over previous
//
#include <hip/hip_runtime.h>
#include <hip/hip_bf16.h>

// Problem constants
#define BATCH 64
#define CIN   128
#define HIN   56
#define WIN   56
#define COUT  256
#define KSZ   3
#define OHP   54
#define OWP   54
#define NSPAT (OHP * OWP)          // 2916 flat spatial outputs per batch
#define NTILES 23                  // ceil(2916/128)
#define KDIM  (CIN * KSZ * KSZ)    // 1152

typedef short bf16x8 __attribute__((ext_vector_type(8)));
typedef float f32x4  __attribute__((ext_vector_type(4)));

static __device__ __forceinline__ unsigned short f2bf(float f) {
    unsigned v = __float_as_uint(f);
    v += 0x7FFFu + ((v >> 16) & 1u);
    return (unsigned short)(v >> 16);
}

static __device__ __forceinline__ void gl_lds16(const void* g, void* l) {
    __builtin_amdgcn_global_load_lds(
        (const __attribute__((address_space(1))) void*)g,
        (__attribute__((address_space(3))) void*)l, 16, 0, 0);
}

// ---------------- kernel 1: per-block max |w| (no atomics, no init needed) ----------------
__global__ __launch_bounds__(256) void maxabs_kernel(const float* __restrict__ w,
                                                     float* __restrict__ blockmax, int n) {
    float m = 0.f;
    for (int i = blockIdx.x * 256 + threadIdx.x; i < n; i += gridDim.x * 256)
        m = fmaxf(m, fabsf(w[i]));
    for (int off = 32; off > 0; off >>= 1)
        m = fmaxf(m, __shfl_down(m, off));
    __shared__ float red[4];
    if ((threadIdx.x & 63) == 0) red[threadIdx.x >> 6] = m;
    __syncthreads();
    if (threadIdx.x == 0)
        blockmax[blockIdx.x] = fmaxf(fmaxf(red[0], red[1]), fmaxf(red[2], red[3]));
}

// ---------------- kernel 2: finish max-reduce + ternary quantize + repack ----------------
// qw layout: [co][(kh*3+kw)*128 + ci] bf16
__global__ __launch_bounds__(256) void quant_kernel(const float* __restrict__ w,
                                                    const float* __restrict__ wp,
                                                    const float* __restrict__ wn,
                                                    const float* __restrict__ blockmax,
                                                    unsigned short* __restrict__ qw) {
    __shared__ float red[4];
    float m = blockmax[threadIdx.x];          // 256 partial maxima
    for (int off = 32; off > 0; off >>= 1)
        m = fmaxf(m, __shfl_down(m, off));
    if ((threadIdx.x & 63) == 0) red[threadIdx.x >> 6] = m;
    __syncthreads();
    float t = 0.05f * fmaxf(fmaxf(red[0], red[1]), fmaxf(red[2], red[3]));

    int idx = blockIdx.x * 256 + threadIdx.x;   // grid covers exactly 294912
    float p = fabsf(wp[0]), nn = fabsf(wn[0]);
    float v = w[idx];
    float q = (v > t) ? p : ((v < -t) ? -nn : 0.0f);
    int co  = idx / KDIM;
    int rem = idx - co * KDIM;
    int ci  = rem / 9;
    int kk  = rem - ci * 9;            // kh*3+kw
    qw[co * KDIM + kk * CIN + ci] = f2bf(q);
}

// ---------------- kernel 3: x fp32 NCHW -> bf16 NHWC (x_t[b][h][w][ci]) ----------------
__global__ __launch_bounds__(256) void cast_nhwc_kernel(const float* __restrict__ x,
                                                        unsigned* __restrict__ xt_u32) {
    int b = blockIdx.x / HIN;
    int h = blockIdx.x - b * HIN;
    __shared__ float xs[CIN][57];
#pragma unroll
    for (int it = 0; it < 7; ++it) {
        int id = it * 256 + threadIdx.x;       // 1792 float4 chunks: 128 ci x 14
        int ci = id / 14;
        int wq = (id - ci * 14) * 4;
        float4 v = *(const float4*)(x + (((size_t)(b * CIN + ci)) * HIN + h) * WIN + wq);
        xs[ci][wq + 0] = v.x; xs[ci][wq + 1] = v.y;
        xs[ci][wq + 2] = v.z; xs[ci][wq + 3] = v.w;
    }
    __syncthreads();
#pragma unroll
    for (int it = 0; it < 7; ++it) {
        int id = it * 256 + threadIdx.x;       // 56 w x 32 chunks of 4 ci
        int w_ = id >> 5;
        int cq = (id & 31) * 4;
        unsigned u0 = (unsigned)f2bf(xs[cq + 0][w_]) | ((unsigned)f2bf(xs[cq + 1][w_]) << 16);
        unsigned u1 = (unsigned)f2bf(xs[cq + 2][w_]) | ((unsigned)f2bf(xs[cq + 3][w_]) << 16);
        uint2 val; val.x = u0; val.y = u1;
        *(uint2*)&xt_u32[((size_t)(b * HIN + h) * WIN + w_) * 64 + (id & 31) * 2] = val;
    }
}

// ---------------- kernel 4: implicit-GEMM MFMA conv ----------------
// BM=128 (co), BN=128 (flat spatial), BK=64; 18 K-iters, 32 MFMA/iter.
// grid = 2944 = 8 XCD x 368; blocks sharing b pinned to one XCD (b%8 == blockIdx%8).
// (Proven round-0 structure — 3 blocks/CU hides the barrier drain. Only change vs
//  round-0: epilogue store order is now co-row-major so each wave emits 256B
//  contiguous per output row back-to-back -> full 128B lines complete in L2,
//  killing the measured 1.5x WRITE_SIZE amplification.)
__global__ __launch_bounds__(256, 3) void conv_mfma_kernel(const unsigned short* __restrict__ xt,
                                                           const unsigned short* __restrict__ qw,
                                                           const float* __restrict__ bias,
                                                           float* __restrict__ out) {
    int xcd = blockIdx.x & 7;
    int k   = blockIdx.x >> 3;          // 0..367
    int g   = k / 46;                   // 0..7
    int r   = k - g * 46;               // 0..45
    int b   = g * 8 + xcd;
    int mt  = r / 23;
    int nt  = r - mt * 23;

    __shared__ __align__(16) unsigned short As[128 * 64];   // [row][64] rows = co
    __shared__ __align__(16) unsigned short Bs[128 * 64];   // [row][64] rows = flat n

    int t    = threadIdx.x;
    int wave = t >> 6, lane = t & 63;
    int wm   = wave >> 1, wcol = wave & 1;
    int quad = lane >> 4, r16 = lane & 15;

    // staging: call c stages chunk p = c*256 + t; row = p>>3 = c*32 + (t>>3),
    // phys chunk-in-row = t&7, fetched logical chunk = (t&7) ^ (row&7)  [XOR-8 swizzle]
    int row0 = t >> 3;                         // 0..31
    int lc   = (t & 7) ^ (row0 & 7);           // c*32 doesn't change row&7

    const unsigned short* Ab = qw + (size_t)(mt * 128 + row0) * KDIM + lc * 8;
    const unsigned short* Bb[4];
#pragma unroll
    for (int c = 0; c < 4; ++c) {
        unsigned n = nt * 128 + c * 32 + row0;
        if (n > NSPAT - 1) n = NSPAT - 1;
        unsigned oh = n / OWP, ow = n - oh * OWP;
        Bb[c] = xt + ((size_t)(b * HIN + oh) * WIN + ow) * CIN + lc * 8;
    }

    f32x4 acc[4][4] = {};

#pragma unroll
    for (int kk = 0; kk < 18; ++kk) {
        int slice = kk >> 1;
        int kh = slice / 3, kw = slice - kh * 3;
        int boff = (kh * WIN + kw) * CIN + (kk & 1) * 64;   // shorts
        int aoff = kk * 64;                                 // shorts

#pragma unroll
        for (int c = 0; c < 4; ++c) {
            gl_lds16(Ab + aoff + c * 32 * KDIM, (char*)As + c * 4096 + wave * 1024);
            gl_lds16(Bb[c] + boff,              (char*)Bs + c * 4096 + wave * 1024);
        }
        __syncthreads();

#pragma unroll
        for (int s = 0; s < 2; ++s) {
            int pc = ((s * 4 + quad) ^ (r16 & 7)) * 8;      // phys chunk offset (shorts)
            bf16x8 af[4], bfr[4];
#pragma unroll
            for (int i = 0; i < 4; ++i)
                af[i] = *(const bf16x8*)&As[(wm * 64 + i * 16 + r16) * 64 + pc];
#pragma unroll
            for (int j = 0; j < 4; ++j)
                bfr[j] = *(const bf16x8*)&Bs[(wcol * 64 + j * 16 + r16) * 64 + pc];
#pragma unroll
            for (int i = 0; i < 4; ++i)
#pragma unroll
                for (int j = 0; j < 4; ++j)
                    acc[i][j] = __builtin_amdgcn_mfma_f32_16x16x32_bf16(af[i], bfr[j], acc[i][j], 0, 0, 0);
        }
        __syncthreads();
    }

    // ---- epilogue: D row m = quad*4 + r, col n = r16 (layout verified R1) ----
    // Store order: for each output row (co), emit all 4 j-segments (4 x 64B = 256B
    // contiguous per wave) back-to-back so L2 lines fill completely before eviction.
#pragma unroll
    for (int i = 0; i < 4; ++i) {
        int co_base = mt * 128 + wm * 64 + i * 16 + quad * 4;
        float4 bv = *(const float4*)(bias + co_base);
        float bvd[4] = {bv.x, bv.y, bv.z, bv.w};
#pragma unroll
        for (int d = 0; d < 4; ++d) {
            size_t rowb = (size_t)(b * COUT + co_base + d) * NSPAT;
#pragma unroll
            for (int j = 0; j < 4; ++j) {
                unsigned n = nt * 128 + wcol * 64 + j * 16 + r16;
                if (n < NSPAT)
                    out[rowb + n] = acc[i][j][d] + bvd[d];
            }
        }
    }
}

extern "C" void kernel_launch(void* const* d_in, const int* in_sizes, int n_in,
                              void* d_out, int out_size, void* d_ws, size_t ws_size,
                              hipStream_t stream) {
    const float* x      = (const float*)d_in[0];
    const float* weight = (const float*)d_in[1];
    const float* bias   = (const float*)d_in[2];
    const float* wp     = (const float*)d_in[3];
    const float* wn     = (const float*)d_in[4];
    float* out          = (float*)d_out;

    // ws layout: [0,1024) blockmax fp32[256] | [1024,..) qw bf16 [256][1152]
    //            [590848,..) x_t bf16 [64][56][56][128]
    float*          bmax = (float*)d_ws;
    unsigned short* qw   = (unsigned short*)((char*)d_ws + 1024);
    unsigned short* xt   = (unsigned short*)((char*)d_ws + 590848);

    maxabs_kernel<<<256, 256, 0, stream>>>(weight, bmax, COUT * KDIM);
    quant_kernel<<<(COUT * KDIM) / 256, 256, 0, stream>>>(weight, wp, wn, bmax, qw);
    cast_nhwc_kernel<<<BATCH * HIN, 256, 0, stream>>>(x, (unsigned*)xt);
    conv_mfma_kernel<<<2 * BATCH * NTILES, 256, 0, stream>>>(xt, qw, bias, out);
}